// Round 3
// baseline (156.361 us; speedup 1.0000x reference)
//
#include <hip/hip_runtime.h>
#include <stdint.h>

#define Nn 4
#define Cc 64
#define LL 4096   // H*W
#define KK 256    // feature dim: 64 channels * 4 causal taps
#define TRI2 528  // 32*33/2 triangular 128x128 tile pairs per batch

typedef _Float16 half8 __attribute__((ext_vector_type(8)));
typedef float f32x16 __attribute__((ext_vector_type(16)));
typedef float f32x4 __attribute__((ext_vector_type(4)));           // 16B aligned
typedef unsigned short ushort8v __attribute__((ext_vector_type(8)));

__device__ __forceinline__ unsigned f2ord(float f) {
    unsigned u = __float_as_uint(f);
    return u ^ ((u & 0x80000000u) ? 0xFFFFFFFFu : 0x80000000u);
}
__device__ __forceinline__ float ord2f(unsigned o) {
    unsigned u = (o & 0x80000000u) ? (o ^ 0x80000000u) : ~o;
    return __uint_as_float(u);
}
__device__ __forceinline__ unsigned short h2u(_Float16 h) {
    union { _Float16 f; unsigned short u; } x; x.f = h; return x.u;
}

// Kernel 1: normalized masked context vectors, split fp16 hi/lo, both pre-scaled:
//   Vh' = 2048*fp16(v)  (exact pow2),  Vl = fp16((v - fp16(v)) * 2048)
// Both MFMA-FRAGMENT-PACKED (see R2 notes):
//   addr(n,l,k) = (((n*128+(l>>5))*16+(k>>4))<<9) + ((k>>3)&1)*256 + (l&31)*8 + (k&7)
// ALSO emits yhatT[n][l][c] (channel-contiguous transpose) for writeout's gather.
// XCD-pinned and zeroes its slice of `best`.
__global__ __launch_bounds__(256) void build_v(const float* __restrict__ yhat,
                                               unsigned short* __restrict__ VhT,
                                               unsigned short* __restrict__ VlT,
                                               float* __restrict__ yhatT,
                                               unsigned long long* __restrict__ best) {
    int blk = blockIdx.x;                       // 0..1023
    int xcd = blk & 7;
    int n = xcd >> 1;
    int i64 = (blk >> 3) + (xcd & 1) * 128;     // 0..255; block covers l = i64*16 ..+16
    int tid = threadIdx.x;
    if (tid < 16) best[(size_t)n * LL + i64 * 16 + tid] = 0ull;

    int cg = tid & 15;           // channel group 0..15 (4 channels each) == k16 chunk
    int l = i64 * 16 + (tid >> 4);
    int y = l >> 6, x = l & 63;
    const float* src = yhat + (size_t)n * (Cc * LL);

    float vals[16];
    float ctr[4];
    float sumsq = 0.f;
#pragma unroll
    for (int ci = 0; ci < 4; ++ci) {
        const float* p = src + (cg * 4 + ci) * LL;
        float t0 = (y > 0 && x > 0)  ? p[l - 65] : 0.f;
        float t1 = (y > 0)           ? p[l - 64] : 0.f;
        float t2 = (y > 0 && x < 63) ? p[l - 63] : 0.f;
        float t3 = (x > 0)           ? p[l - 1]  : 0.f;
        ctr[ci] = p[l];
        vals[ci * 4 + 0] = t0; vals[ci * 4 + 1] = t1;
        vals[ci * 4 + 2] = t2; vals[ci * 4 + 3] = t3;
        sumsq += t0 * t0 + t1 * t1 + t2 * t2 + t3 * t3;
    }
    sumsq += __shfl_xor(sumsq, 1, 64);
    sumsq += __shfl_xor(sumsq, 2, 64);
    sumsq += __shfl_xor(sumsq, 4, 64);
    sumsq += __shfl_xor(sumsq, 8, 64);
    float inv = 1.f / fmaxf(sqrtf(sumsq), 1e-12f);

    // channel-contiguous transpose for writeout (16 threads x 16B = 256B/row)
    f32x4 cv; cv.x = ctr[0]; cv.y = ctr[1]; cv.z = ctr[2]; cv.w = ctr[3];
    *(f32x4*)(yhatT + ((size_t)n * LL + l) * 64 + cg * 4) = cv;

    // fragment-packed destination: 1KB chunk (rowblk,cg) + row slot
    size_t pk = ((((size_t)n * 128 + (l >> 5)) * 16 + cg) << 9) + (l & 31) * 8;
    unsigned short* dh = VhT + pk;
    unsigned short* dl = VlT + pk;
    ushort8v hA, hB, lA, lB;
#pragma unroll
    for (int kk = 0; kk < 16; ++kk) {           // kk = ci*4 + tp = k within chunk
        float v = vals[kk] * inv;
        _Float16 h = (fabsf(v) < 6.1035e-5f) ? (_Float16)0 : (_Float16)v;
        _Float16 lo = (_Float16)((v - (float)h) * 2048.0f);
        unsigned short hu = h2u(h * (_Float16)2048.0f);   // exact pow2 scale
        unsigned short lu = h2u(lo);
        if (kk < 8) { hA[kk] = hu; lA[kk] = lu; }
        else        { hB[kk - 8] = hu; lB[kk - 8] = lu; }
    }
    *(ushort8v*)(dh)       = hA;   // k8-half 0
    *(ushort8v*)(dh + 256) = hB;   // k8-half 1 (+256 halves = +512B)
    *(ushort8v*)(dl)       = lA;
    *(ushort8v*)(dl + 256) = lB;
}

// ---- simmax helpers: register double-buffer set load / MFMA cluster ----
__device__ __forceinline__ void loadset(const unsigned short* Ah0, const unsigned short* Ah1,
                                        const unsigned short* Al0, const unsigned short* Al1,
                                        const unsigned short* Bh0, const unsigned short* Bh1,
                                        const unsigned short* Bl0, const unsigned short* Bl1,
                                        int le,
                                        half8 (&al)[2][2], half8 (&ah)[2][2],
                                        half8 (&bl)[2][2], half8 (&bh)[2][2]) {
    // first-use order: pass1 consumes al,bh; pass2 ah,bl
    al[0][0] = *(const half8*)(Al0 + le);       al[0][1] = *(const half8*)(Al0 + 512 + le);
    al[1][0] = *(const half8*)(Al1 + le);       al[1][1] = *(const half8*)(Al1 + 512 + le);
    bh[0][0] = *(const half8*)(Bh0 + le);       bh[0][1] = *(const half8*)(Bh0 + 512 + le);
    bh[1][0] = *(const half8*)(Bh1 + le);       bh[1][1] = *(const half8*)(Bh1 + 512 + le);
    ah[0][0] = *(const half8*)(Ah0 + le);       ah[0][1] = *(const half8*)(Ah0 + 512 + le);
    ah[1][0] = *(const half8*)(Ah1 + le);       ah[1][1] = *(const half8*)(Ah1 + 512 + le);
    bl[0][0] = *(const half8*)(Bl0 + le);       bl[0][1] = *(const half8*)(Bl0 + 512 + le);
    bl[1][0] = *(const half8*)(Bl1 + le);       bl[1][1] = *(const half8*)(Bl1 + 512 + le);
}

__device__ __forceinline__ void mfmaset(half8 (&al)[2][2], half8 (&ah)[2][2],
                                        half8 (&bl)[2][2], half8 (&bh)[2][2],
                                        f32x16 (&acc)[2][2]) {
    // accumulation order identical to all prior versions (bit-exact)
    __builtin_amdgcn_s_setprio(1);
#pragma unroll
    for (int kc = 0; kc < 2; ++kc)
#pragma unroll
        for (int r = 0; r < 2; ++r)
#pragma unroll
            for (int c = 0; c < 2; ++c)
                acc[r][c] = __builtin_amdgcn_mfma_f32_32x32x16_f16(al[r][kc], bh[c][kc], acc[r][c], 0, 0, 0);
#pragma unroll
    for (int kc = 0; kc < 2; ++kc)
#pragma unroll
        for (int r = 0; r < 2; ++r)
#pragma unroll
            for (int c = 0; c < 2; ++c)
                acc[r][c] = __builtin_amdgcn_mfma_f32_32x32x16_f16(ah[r][kc], bl[c][kc], acc[r][c], 0, 0, 0);
#pragma unroll
    for (int kc = 0; kc < 2; ++kc)
#pragma unroll
        for (int r = 0; r < 2; ++r)
#pragma unroll
            for (int c = 0; c < 2; ++c)
                acc[r][c] = __builtin_amdgcn_mfma_f32_32x32x16_f16(ah[r][kc], bh[c][kc], acc[r][c], 0, 0, 0);
    __builtin_amdgcn_s_setprio(0);
}

// Kernel 2: triangular 128x128-tiled similarity-max via split-fp16 32x32x16 MFMA.
// acc = Al'Bh' + Ah'Bl + Ah'Bh' = 2^22 * v1.v2 ; val = acc * 2^-22.
// NO LDS/barriers; REGISTER double-buffered: kstep t+1's 16 fragment loads are
// issued before kstep t's MFMA cluster -> counted vmcnt keeps 16 loads in
// flight under 192 MFMA cycles (L2 latency hidden per-wave).
// Bases hoisted to SGPR via readfirstlane; per-kstep advance is scalar adds.
__global__ __launch_bounds__(256) void simmax(const unsigned short* __restrict__ Vh,
                                              const unsigned short* __restrict__ Vl,
                                              unsigned long long* __restrict__ best) {
    int bx = blockIdx.x;              // 0..2111
    int xcd = bx & 7, idx = bx >> 3;  // XCD-pin: each XCD owns half of one batch
    int n = xcd >> 1;
    int t = (xcd & 1) * 264 + idx;    // 0..527
    int j = (int)((sqrtf(8.f * (float)t + 1.f) - 1.f) * 0.5f);
    while ((j + 1) * (j + 2) / 2 <= t) ++j;
    while (j * (j + 1) / 2 > t) --j;
    int i = t - j * (j + 1) / 2;
    int l0 = i * 128, m0 = j * 128;

    int tid = threadIdx.x;
    int w = tid >> 6, lane = tid & 63;
    int r5 = lane & 31, h5 = lane >> 5;
    int rw = (w & 1) * 64;    // wave rows (l)
    int cw = (w >> 1) * 64;   // wave cols (m)
    if ((i == j) && (rw == 64) && (cw == 0)) return;  // fully l>m: nothing to do

    const unsigned short* VhB = Vh + (size_t)n * (LL * KK);
    const unsigned short* VlB = Vl + (size_t)n * (LL * KK);

    // wave-uniform rowblock bases -> SGPR
    int aRow = __builtin_amdgcn_readfirstlane((l0 + rw) >> 5);
    int bRow = __builtin_amdgcn_readfirstlane((m0 + cw) >> 5);
    const unsigned short* Ah0 = VhB + ((size_t)aRow << 13);
    const unsigned short* Ah1 = Ah0 + 8192;
    const unsigned short* Al0 = VlB + ((size_t)aRow << 13);
    const unsigned short* Al1 = Al0 + 8192;
    const unsigned short* Bh0 = VhB + ((size_t)bRow << 13);
    const unsigned short* Bh1 = Bh0 + 8192;
    const unsigned short* Bl0 = VlB + ((size_t)bRow << 13);
    const unsigned short* Bl1 = Bl0 + 8192;
    int le = lane * 8;                // per-lane element offset (halves)

    f32x16 acc[2][2];
#pragma unroll
    for (int r = 0; r < 2; ++r)
#pragma unroll
        for (int c = 0; c < 2; ++c) acc[r][c] = (f32x16)0.f;

    half8 alA[2][2], ahA[2][2], blA[2][2], bhA[2][2];   // set A
    half8 alB[2][2], ahB[2][2], blB[2][2], bhB[2][2];   // set B

#define BUMP() do { Ah0 += 1024; Ah1 += 1024; Al0 += 1024; Al1 += 1024; \
                    Bh0 += 1024; Bh1 += 1024; Bl0 += 1024; Bl1 += 1024; } while (0)

    loadset(Ah0, Ah1, Al0, Al1, Bh0, Bh1, Bl0, Bl1, le, alA, ahA, blA, bhA);
    BUMP();
#pragma unroll 1
    for (int it = 0; it < 4; ++it) {
        loadset(Ah0, Ah1, Al0, Al1, Bh0, Bh1, Bl0, Bl1, le, alB, ahB, blB, bhB);
        BUMP();
        mfmaset(alA, ahA, blA, bhA, acc);
        if (it < 3) {
            loadset(Ah0, Ah1, Al0, Al1, Bh0, Bh1, Bl0, Bl1, le, alA, ahA, blA, bhA);
            BUMP();
        }
        mfmaset(alB, ahB, blB, bhB, acc);
    }
#undef BUMP

    unsigned long long* bb = best + (size_t)n * LL;
    const float s = 1.f / 4194304.f;   // 2^-22
#pragma unroll
    for (int c = 0; c < 2; ++c) {
        int m = m0 + cw + c * 32 + r5;
        unsigned long long key = 0ull;
#pragma unroll
        for (int r = 0; r < 2; ++r)
#pragma unroll
            for (int g = 0; g < 16; ++g) {
                int l = l0 + rw + r * 32 + (g & 3) + 8 * (g >> 2) + 4 * h5;
                if (l < m) {
                    float v = acc[r][c][g] * s;
                    unsigned long long k2 =
                        ((unsigned long long)f2ord(v) << 32) |
                        (unsigned long long)(0xFFFFFFFFu - (unsigned)l);
                    key = (k2 > key) ? k2 : key;
                }
            }
        unsigned long long o = __shfl_xor(key, 32, 64);
        key = (o > key) ? o : key;
        if (h5 == 0 && key != 0ull) atomicMax(bb + m, key);
    }
}

// Kernel 3: unpack best, write S, U, ref_unfold, arg. Gather now reads the
// channel-contiguous yhatT with lanes spanning c (coalesced 256B runs per m),
// transposes [patch][c] -> [f][m] through padded LDS, stores Rout coalesced.
// Block = (n, 16 m's). 1024 blocks, XCD-pinned.
__global__ __launch_bounds__(256) void writeout(const float* __restrict__ yhatT,
                                                const float* __restrict__ yprob,
                                                const unsigned long long* __restrict__ best,
                                                float* __restrict__ out) {
    __shared__ float P[576 * 17];             // [f][m] stride 17 (bank-spread), 39168B

    int blk = blockIdx.x;                     // 0..1023
    int xcd = blk & 7;
    int n = xcd >> 1;
    int mb = (blk >> 3) + (xcd & 1) * 128;    // 0..255
    int m0 = mb * 16;
    int tid = threadIdx.x;
    int ml = tid >> 4;                        // m_local 0..15
    int cs = (tid & 15) * 4;                  // channel start 0,4,..,60
    int m = m0 + ml;

    unsigned long long key = best[(size_t)n * LL + m];
    unsigned l = 0xFFFFFFFFu - (unsigned)(key & 0xFFFFFFFFull);
    float val = ord2f((unsigned)(key >> 32));
    bool zero = (m == 0);
    if (zero) l = 0;
    int ly = (int)(l >> 6), lx = (int)(l & 63);

    float* Sout = out;                       // [4,1,64,64]
    float* Uout = out + 16384;               // [4,1,64,64]
    float* Rout = out + 32768;               // [4,576,4096]
    float* Aout = out + 9469952;             // [4,4096] as float values

    if (cs == 0) {                            // one thread per m
        float S = zero ? 1e-8f : fminf(fmaxf(val, 1e-8f), 1.0f);
        float U = zero ? 1e-8f : fminf(fmaxf(yprob[(size_t)n * LL + l], 1e-8f), 1.0f);
        Sout[(size_t)n * LL + m] = S;
        Uout[(size_t)n * LL + m] = U;
        Aout[(size_t)n * LL + m] = zero ? -1.0f : (float)l;
    }

    // phase 1: gather 3x3 patch rows channel-contiguous, scatter into LDS [f][m]
    const float* T = yhatT + ((size_t)n * LL) * 64;
#pragma unroll
    for (int i = 0; i < 3; ++i) {
        int yy = ly + i - 1;
        bool rok = (!zero) && (yy >= 0) && (yy < 64);
#pragma unroll
        for (int jj = 0; jj < 3; ++jj) {
            int xx = lx + jj - 1;
            f32x4 v; v.x = 0.f; v.y = 0.f; v.z = 0.f; v.w = 0.f;
            if (rok && xx >= 0 && xx < 64)
                v = *(const f32x4*)(T + ((size_t)(yy * 64 + xx)) * 64 + cs);
            int ij = i * 3 + jj;
            P[((cs + 0) * 9 + ij) * 17 + ml] = v.x;
            P[((cs + 1) * 9 + ij) * 17 + ml] = v.y;
            P[((cs + 2) * 9 + ij) * 17 + ml] = v.z;
            P[((cs + 3) * 9 + ij) * 17 + ml] = v.w;
        }
    }
    __syncthreads();

    // phase 2: coalesced Rout stores (wave = 4 f x 16 m -> 4x64B segments)
    float* R = Rout + (size_t)n * (576 * LL) + m0;
    int fl = tid >> 4;                        // f offset within iteration
    int mm2 = tid & 15;
#pragma unroll 1
    for (int it2 = 0; it2 < 36; ++it2) {
        int f = it2 * 16 + fl;
        float v = P[f * 17 + mm2];
        __builtin_nontemporal_store(v, R + (size_t)f * LL + mm2);
    }
}

extern "C" void kernel_launch(void* const* d_in, const int* in_sizes, int n_in,
                              void* d_out, int out_size, void* d_ws, size_t ws_size,
                              hipStream_t stream) {
    const float* yhat  = (const float*)d_in[0];
    const float* yprob = (const float*)d_in[1];
    float* out = (float*)d_out;

    unsigned short* VhT = (unsigned short*)d_ws;                       // 8 MiB (fragment-packed)
    unsigned short* VlT = (unsigned short*)((char*)d_ws + 8388608);    // 8 MiB (fragment-packed)
    unsigned long long* best =
        (unsigned long long*)((char*)d_ws + 16777216);                 // 128 KiB
    float* yhatT = (float*)((char*)d_ws + 16908288);                   // 4 MiB transpose

    build_v<<<1024, 256, 0, stream>>>(yhat, VhT, VlT, yhatT, best);
    simmax<<<Nn * TRI2, 256, 0, stream>>>(VhT, VlT, best);
    writeout<<<1024, 256, 0, stream>>>(yhatT, yprob, best, out);
}

// Round 4
// 153.495 us; speedup vs baseline: 1.0187x; 1.0187x over previous
//
#include <hip/hip_runtime.h>
#include <stdint.h>

#define Nn 4
#define Cc 64
#define LL 4096   // H*W
#define KK 256    // feature dim: 64 channels * 4 causal taps
#define TRI2 528  // 32*33/2 triangular 128x128 tile pairs per batch

typedef _Float16 half8 __attribute__((ext_vector_type(8)));
typedef float f32x16 __attribute__((ext_vector_type(16)));
typedef float f32x4 __attribute__((ext_vector_type(4)));           // 16B aligned
typedef unsigned short ushort8v __attribute__((ext_vector_type(8)));

__device__ __forceinline__ unsigned f2ord(float f) {
    unsigned u = __float_as_uint(f);
    return u ^ ((u & 0x80000000u) ? 0xFFFFFFFFu : 0x80000000u);
}
__device__ __forceinline__ float ord2f(unsigned o) {
    unsigned u = (o & 0x80000000u) ? (o ^ 0x80000000u) : ~o;
    return __uint_as_float(u);
}
__device__ __forceinline__ unsigned short h2u(_Float16 h) {
    union { _Float16 f; unsigned short u; } x; x.f = h; return x.u;
}

// Kernel 1: normalized masked context vectors, split fp16 hi/lo, both pre-scaled:
//   Vh' = 2048*fp16(v)  (exact pow2),  Vl = fp16((v - fp16(v)) * 2048)
// Both MFMA-FRAGMENT-PACKED:
//   addr(n,l,k) = (((n*128+(l>>5))*16+(k>>4))<<9) + ((k>>3)&1)*256 + (l&31)*8 + (k&7)
// ALSO emits yhatT[n][l][c] (channel-contiguous transpose) for writeout's gather.
// XCD-pinned and zeroes its slice of `best`.
__global__ __launch_bounds__(256) void build_v(const float* __restrict__ yhat,
                                               unsigned short* __restrict__ VhT,
                                               unsigned short* __restrict__ VlT,
                                               float* __restrict__ yhatT,
                                               unsigned long long* __restrict__ best) {
    int blk = blockIdx.x;                       // 0..1023
    int xcd = blk & 7;
    int n = xcd >> 1;
    int i64 = (blk >> 3) + (xcd & 1) * 128;     // 0..255; block covers l = i64*16 ..+16
    int tid = threadIdx.x;
    if (tid < 16) best[(size_t)n * LL + i64 * 16 + tid] = 0ull;

    int cg = tid & 15;           // channel group 0..15 (4 channels each) == k16 chunk
    int l = i64 * 16 + (tid >> 4);
    int y = l >> 6, x = l & 63;
    const float* src = yhat + (size_t)n * (Cc * LL);

    float vals[16];
    float ctr[4];
    float sumsq = 0.f;
#pragma unroll
    for (int ci = 0; ci < 4; ++ci) {
        const float* p = src + (cg * 4 + ci) * LL;
        float t0 = (y > 0 && x > 0)  ? p[l - 65] : 0.f;
        float t1 = (y > 0)           ? p[l - 64] : 0.f;
        float t2 = (y > 0 && x < 63) ? p[l - 63] : 0.f;
        float t3 = (x > 0)           ? p[l - 1]  : 0.f;
        ctr[ci] = p[l];
        vals[ci * 4 + 0] = t0; vals[ci * 4 + 1] = t1;
        vals[ci * 4 + 2] = t2; vals[ci * 4 + 3] = t3;
        sumsq += t0 * t0 + t1 * t1 + t2 * t2 + t3 * t3;
    }
    sumsq += __shfl_xor(sumsq, 1, 64);
    sumsq += __shfl_xor(sumsq, 2, 64);
    sumsq += __shfl_xor(sumsq, 4, 64);
    sumsq += __shfl_xor(sumsq, 8, 64);
    float inv = 1.f / fmaxf(sqrtf(sumsq), 1e-12f);

    // channel-contiguous transpose for writeout (16 threads x 16B = 256B/row)
    f32x4 cv; cv.x = ctr[0]; cv.y = ctr[1]; cv.z = ctr[2]; cv.w = ctr[3];
    *(f32x4*)(yhatT + ((size_t)n * LL + l) * 64 + cg * 4) = cv;

    // fragment-packed destination: 1KB chunk (rowblk,cg) + row slot
    size_t pk = ((((size_t)n * 128 + (l >> 5)) * 16 + cg) << 9) + (l & 31) * 8;
    unsigned short* dh = VhT + pk;
    unsigned short* dl = VlT + pk;
    ushort8v hA, hB, lA, lB;
#pragma unroll
    for (int kk = 0; kk < 16; ++kk) {           // kk = ci*4 + tp = k within chunk
        float v = vals[kk] * inv;
        _Float16 h = (fabsf(v) < 6.1035e-5f) ? (_Float16)0 : (_Float16)v;
        _Float16 lo = (_Float16)((v - (float)h) * 2048.0f);
        unsigned short hu = h2u(h * (_Float16)2048.0f);   // exact pow2 scale
        unsigned short lu = h2u(lo);
        if (kk < 8) { hA[kk] = hu; lA[kk] = lu; }
        else        { hB[kk - 8] = hu; lB[kk - 8] = lu; }
    }
    *(ushort8v*)(dh)       = hA;   // k8-half 0
    *(ushort8v*)(dh + 256) = hB;   // k8-half 1 (+256 halves = +512B)
    *(ushort8v*)(dl)       = lA;
    *(ushort8v*)(dl + 256) = lB;
}

// ---- simmax: MFMA cluster (accumulation order bit-exact vs all prior versions) ----
__device__ __forceinline__ void mfmaset(half8 (&al)[2][2], half8 (&ah)[2][2],
                                        half8 (&bl)[2][2], half8 (&bh)[2][2],
                                        f32x16 (&acc)[2][2]) {
    __builtin_amdgcn_s_setprio(1);
#pragma unroll
    for (int kc = 0; kc < 2; ++kc)
#pragma unroll
        for (int r = 0; r < 2; ++r)
#pragma unroll
            for (int c = 0; c < 2; ++c)
                acc[r][c] = __builtin_amdgcn_mfma_f32_32x32x16_f16(al[r][kc], bh[c][kc], acc[r][c], 0, 0, 0);
#pragma unroll
    for (int kc = 0; kc < 2; ++kc)
#pragma unroll
        for (int r = 0; r < 2; ++r)
#pragma unroll
            for (int c = 0; c < 2; ++c)
                acc[r][c] = __builtin_amdgcn_mfma_f32_32x32x16_f16(ah[r][kc], bl[c][kc], acc[r][c], 0, 0, 0);
#pragma unroll
    for (int kc = 0; kc < 2; ++kc)
#pragma unroll
        for (int r = 0; r < 2; ++r)
#pragma unroll
            for (int c = 0; c < 2; ++c)
                acc[r][c] = __builtin_amdgcn_mfma_f32_32x32x16_f16(ah[r][kc], bh[c][kc], acc[r][c], 0, 0, 0);
    __builtin_amdgcn_s_setprio(0);
}

// Kernel 2: triangular 128x128-tiled similarity-max via split-fp16 32x32x16 MFMA.
// acc = Al'Bh' + Ah'Bl + Ah'Bh' = 2^22 * v1.v2 ; val = acc * 2^-22.
// NEW: per kstep the block stages its 32 x 1KB fragment chunks ONCE into LDS via
// global_load_lds (wave-uniform base + lane*16B == our packed layout exactly),
// double-buffered (64KB), prefetched one kstep ahead; waves read fragments from
// LDS (lane-contiguous 16B, conflict-free). Halves VMEM traffic (de-dups the
// 2x A / 2x B fragment sharing) and hides L2 latency under the MFMA cluster.
// One barrier per kstep; its vmcnt(0) drain is cheap (staging issued >=192cy prior).
// Fragment bytes and per-acc-element accumulation order are bit-identical.
// Chunk id c in [0,32): side=c>>4 (A/B), rowblk rb=(c>>2)&3, lo=(c>>1)&1, kc=c&1.
__global__ __launch_bounds__(256) void simmax(const unsigned short* __restrict__ Vh,
                                              const unsigned short* __restrict__ Vl,
                                              unsigned long long* __restrict__ best) {
    __shared__ __align__(16) unsigned short S[32768];   // 2 bufs x 32 chunks x 1KB = 64KB

    int bx = blockIdx.x;              // 0..2111
    int xcd = bx & 7, idx = bx >> 3;  // XCD-pin: each XCD owns half of one batch
    int n = xcd >> 1;
    int t = (xcd & 1) * 264 + idx;    // 0..527
    int j = (int)((sqrtf(8.f * (float)t + 1.f) - 1.f) * 0.5f);
    while ((j + 1) * (j + 2) / 2 <= t) ++j;
    while (j * (j + 1) / 2 > t) --j;
    int i = t - j * (j + 1) / 2;
    int l0 = i * 128, m0 = j * 128;

    int tid = threadIdx.x;
    int w = tid >> 6, lane = tid & 63;
    int r5 = lane & 31, h5 = lane >> 5;
    int rw = (w & 1) * 64;    // wave rows (l)
    int cw = (w >> 1) * 64;   // wave cols (m)
    bool skip = (i == j) && (rw == 64) && (cw == 0);  // fully l>m: no compute

    const unsigned short* VhB = Vh + (size_t)n * (LL * KK);
    const unsigned short* VlB = Vl + (size_t)n * (LL * KK);

    int aRow0 = l0 >> 5;              // block's first A rowblock (of 4)
    int bRow0 = m0 >> 5;              // block's first B rowblock (of 4)

    // wave w stages chunks 8w..8w+7 (waves 0,1 -> A side, waves 2,3 -> B side)
    // per-chunk source base (sans kstep) and LDS slot, precomputed
    const unsigned short* gsrc[8];
    int lslot[8];
#pragma unroll
    for (int q = 0; q < 8; ++q) {
        int c = w * 8 + q;
        int side = c >> 4, rb = (c >> 2) & 3, lo = (c >> 1) & 1, kc = c & 1;
        int rowblk = (side ? bRow0 : aRow0) + rb;
        const unsigned short* base = lo ? VlB : VhB;
        gsrc[q] = base + (((size_t)rowblk * 16 + kc) << 9) + lane * 8;
        lslot[q] = c * 512;
    }

    // wave's fragment chunk ids (within a buffer), as LDS half-offsets
    int arb = (w & 1) * 2;            // wave A rowblock base (0 or 2)
    int brb = (w >> 1) * 2;           // wave B rowblock base

    f32x16 acc[2][2];
#pragma unroll
    for (int r = 0; r < 2; ++r)
#pragma unroll
        for (int c = 0; c < 2; ++c) acc[r][c] = (f32x16)0.f;

    // prologue: stage kstep 0 into buf0
#pragma unroll
    for (int q = 0; q < 8; ++q)
        __builtin_amdgcn_global_load_lds(
            (const __attribute__((address_space(1))) void*)(gsrc[q]),
            (__attribute__((address_space(3))) void*)(S + lslot[q]), 16, 0, 0);
    __syncthreads();

#pragma unroll
    for (int kt = 0; kt < 8; ++kt) {
        const int cur = (kt & 1) * 16384;
        const int nxt = 16384 - cur;

        // 1) prefetch next kstep's 32 chunks into the other buffer
        if (kt < 7) {
            const size_t kadv = (size_t)(kt + 1) * 1024;   // 2 k16-chunks per kstep
#pragma unroll
            for (int q = 0; q < 8; ++q)
                __builtin_amdgcn_global_load_lds(
                    (const __attribute__((address_space(1))) void*)(gsrc[q] + kadv),
                    (__attribute__((address_space(3))) void*)(S + nxt + lslot[q]), 16, 0, 0);
        }

        if (!skip) {
            // 2) fragment reads from LDS buf[cur] (first-use order: al,bh then ah,bl)
            half8 al[2][2], ah[2][2], bl[2][2], bh[2][2];
#pragma unroll
            for (int kc = 0; kc < 2; ++kc)
#pragma unroll
                for (int r = 0; r < 2; ++r) {
                    al[r][kc] = *(const half8*)(S + cur + ((arb + r) * 4 + 2 + kc) * 512 + lane * 8);
                    bh[r][kc] = *(const half8*)(S + cur + (16 + (brb + r) * 4 + kc) * 512 + lane * 8);
                }
#pragma unroll
            for (int kc = 0; kc < 2; ++kc)
#pragma unroll
                for (int r = 0; r < 2; ++r) {
                    ah[r][kc] = *(const half8*)(S + cur + ((arb + r) * 4 + kc) * 512 + lane * 8);
                    bl[r][kc] = *(const half8*)(S + cur + (16 + (brb + r) * 4 + 2 + kc) * 512 + lane * 8);
                }
            // 3) 24 MFMA
            mfmaset(al, ah, bl, bh, acc);
        }

        // 4) one barrier per kstep (drains staging; protects dbuf swap)
        if (kt < 7) __syncthreads();
    }

    if (skip) return;
    unsigned long long* bb = best + (size_t)n * LL;
    const float s = 1.f / 4194304.f;   // 2^-22
#pragma unroll
    for (int c = 0; c < 2; ++c) {
        int m = m0 + cw + c * 32 + r5;
        unsigned long long key = 0ull;
#pragma unroll
        for (int r = 0; r < 2; ++r)
#pragma unroll
            for (int g = 0; g < 16; ++g) {
                int l = l0 + rw + r * 32 + (g & 3) + 8 * (g >> 2) + 4 * h5;
                if (l < m) {
                    float v = acc[r][c][g] * s;
                    unsigned long long k2 =
                        ((unsigned long long)f2ord(v) << 32) |
                        (unsigned long long)(0xFFFFFFFFu - (unsigned)l);
                    key = (k2 > key) ? k2 : key;
                }
            }
        unsigned long long o = __shfl_xor(key, 32, 64);
        key = (o > key) ? o : key;
        if (h5 == 0 && key != 0ull) atomicMax(bb + m, key);
    }
}

// Kernel 3: unpack best, write S, U, ref_unfold, arg. Gather reads the
// channel-contiguous yhatT with lanes spanning c (coalesced 256B runs per m),
// transposes [patch][c] -> [f][m] through padded LDS, stores Rout coalesced.
// Block = (n, 16 m's). 1024 blocks, XCD-pinned.
__global__ __launch_bounds__(256) void writeout(const float* __restrict__ yhatT,
                                                const float* __restrict__ yprob,
                                                const unsigned long long* __restrict__ best,
                                                float* __restrict__ out) {
    __shared__ float P[576 * 17];             // [f][m] stride 17 (bank-spread), 39168B

    int blk = blockIdx.x;                     // 0..1023
    int xcd = blk & 7;
    int n = xcd >> 1;
    int mb = (blk >> 3) + (xcd & 1) * 128;    // 0..255
    int m0 = mb * 16;
    int tid = threadIdx.x;
    int ml = tid >> 4;                        // m_local 0..15
    int cs = (tid & 15) * 4;                  // channel start 0,4,..,60
    int m = m0 + ml;

    unsigned long long key = best[(size_t)n * LL + m];
    unsigned l = 0xFFFFFFFFu - (unsigned)(key & 0xFFFFFFFFull);
    float val = ord2f((unsigned)(key >> 32));
    bool zero = (m == 0);
    if (zero) l = 0;
    int ly = (int)(l >> 6), lx = (int)(l & 63);

    float* Sout = out;                       // [4,1,64,64]
    float* Uout = out + 16384;               // [4,1,64,64]
    float* Rout = out + 32768;               // [4,576,4096]
    float* Aout = out + 9469952;             // [4,4096] as float values

    if (cs == 0) {                            // one thread per m
        float S = zero ? 1e-8f : fminf(fmaxf(val, 1e-8f), 1.0f);
        float U = zero ? 1e-8f : fminf(fmaxf(yprob[(size_t)n * LL + l], 1e-8f), 1.0f);
        Sout[(size_t)n * LL + m] = S;
        Uout[(size_t)n * LL + m] = U;
        Aout[(size_t)n * LL + m] = zero ? -1.0f : (float)l;
    }

    // phase 1: gather 3x3 patch rows channel-contiguous, scatter into LDS [f][m]
    const float* T = yhatT + ((size_t)n * LL) * 64;
#pragma unroll
    for (int i = 0; i < 3; ++i) {
        int yy = ly + i - 1;
        bool rok = (!zero) && (yy >= 0) && (yy < 64);
#pragma unroll
        for (int jj = 0; jj < 3; ++jj) {
            int xx = lx + jj - 1;
            f32x4 v; v.x = 0.f; v.y = 0.f; v.z = 0.f; v.w = 0.f;
            if (rok && xx >= 0 && xx < 64)
                v = *(const f32x4*)(T + ((size_t)(yy * 64 + xx)) * 64 + cs);
            int ij = i * 3 + jj;
            P[((cs + 0) * 9 + ij) * 17 + ml] = v.x;
            P[((cs + 1) * 9 + ij) * 17 + ml] = v.y;
            P[((cs + 2) * 9 + ij) * 17 + ml] = v.z;
            P[((cs + 3) * 9 + ij) * 17 + ml] = v.w;
        }
    }
    __syncthreads();

    // phase 2: coalesced Rout stores (wave = 4 f x 16 m -> 4x64B segments)
    float* R = Rout + (size_t)n * (576 * LL) + m0;
    int fl = tid >> 4;                        // f offset within iteration
    int mm2 = tid & 15;
#pragma unroll 1
    for (int it2 = 0; it2 < 36; ++it2) {
        int f = it2 * 16 + fl;
        float v = P[f * 17 + mm2];
        __builtin_nontemporal_store(v, R + (size_t)f * LL + mm2);
    }
}

extern "C" void kernel_launch(void* const* d_in, const int* in_sizes, int n_in,
                              void* d_out, int out_size, void* d_ws, size_t ws_size,
                              hipStream_t stream) {
    const float* yhat  = (const float*)d_in[0];
    const float* yprob = (const float*)d_in[1];
    float* out = (float*)d_out;

    unsigned short* VhT = (unsigned short*)d_ws;                       // 8 MiB (fragment-packed)
    unsigned short* VlT = (unsigned short*)((char*)d_ws + 8388608);    // 8 MiB (fragment-packed)
    unsigned long long* best =
        (unsigned long long*)((char*)d_ws + 16777216);                 // 128 KiB
    float* yhatT = (float*)((char*)d_ws + 16908288);                   // 4 MiB transpose

    build_v<<<1024, 256, 0, stream>>>(yhat, VhT, VlT, yhatT, best);
    simmax<<<Nn * TRI2, 256, 0, stream>>>(VhT, VlT, best);
    writeout<<<1024, 256, 0, stream>>>(yhatT, yprob, best, out);
}

// Round 6
// 152.744 us; speedup vs baseline: 1.0237x; 1.0049x over previous
//
#include <hip/hip_runtime.h>
#include <stdint.h>

#define Nn 4
#define Cc 64
#define LL 4096   // H*W
#define KK 256    // feature dim: 64 channels * 4 causal taps
#define TRI2 528  // 32*33/2 triangular 128x128 tile pairs per batch

typedef _Float16 half8 __attribute__((ext_vector_type(8)));
typedef float f32x16 __attribute__((ext_vector_type(16)));
typedef float f32x4 __attribute__((ext_vector_type(4)));           // 16B aligned
typedef unsigned short ushort8v __attribute__((ext_vector_type(8)));

__device__ __forceinline__ unsigned f2ord(float f) {
    unsigned u = __float_as_uint(f);
    return u ^ ((u & 0x80000000u) ? 0xFFFFFFFFu : 0x80000000u);
}
__device__ __forceinline__ float ord2f(unsigned o) {
    unsigned u = (o & 0x80000000u) ? (o ^ 0x80000000u) : ~o;
    return __uint_as_float(u);
}
__device__ __forceinline__ unsigned short h2u(_Float16 h) {
    union { _Float16 f; unsigned short u; } x; x.f = h; return x.u;
}

// Raw barrier with COUNTED vmcnt (T4, m201-template pattern): the newest
// glds batches stay in flight across the barrier; only older batches are
// guaranteed landed. lgkmcnt(0) before s_barrier closes the LDS
// read-before-overwrite hazard (reads of the buffer being recycled were
// issued before this point).
__device__ __forceinline__ void pipe_barrier_vm4() {
    asm volatile("s_waitcnt lgkmcnt(0) vmcnt(4)" ::: "memory");
    __builtin_amdgcn_s_barrier();
    __builtin_amdgcn_sched_barrier(0);
}
__device__ __forceinline__ void pipe_barrier_vm0() {
    asm volatile("s_waitcnt lgkmcnt(0) vmcnt(0)" ::: "memory");
    __builtin_amdgcn_s_barrier();
    __builtin_amdgcn_sched_barrier(0);
}

// Kernel 1: normalized masked context vectors, split fp16 hi/lo, both pre-scaled:
//   Vh' = 2048*fp16(v)  (exact pow2),  Vl = fp16((v - fp16(v)) * 2048)
// Both MFMA-FRAGMENT-PACKED:
//   addr(n,l,k) = (((n*128+(l>>5))*16+(k>>4))<<9) + ((k>>3)&1)*256 + (l&31)*8 + (k&7)
// ALSO emits yhatT[n][l][c] (channel-contiguous transpose) for writeout's gather.
// XCD-pinned and zeroes its slice of `best`.
__global__ __launch_bounds__(256) void build_v(const float* __restrict__ yhat,
                                               unsigned short* __restrict__ VhT,
                                               unsigned short* __restrict__ VlT,
                                               float* __restrict__ yhatT,
                                               unsigned long long* __restrict__ best) {
    int blk = blockIdx.x;                       // 0..1023
    int xcd = blk & 7;
    int n = xcd >> 1;
    int i64 = (blk >> 3) + (xcd & 1) * 128;     // 0..255; block covers l = i64*16 ..+16
    int tid = threadIdx.x;
    if (tid < 16) best[(size_t)n * LL + i64 * 16 + tid] = 0ull;

    int cg = tid & 15;           // channel group 0..15 (4 channels each) == k16 chunk
    int l = i64 * 16 + (tid >> 4);
    int y = l >> 6, x = l & 63;
    const float* src = yhat + (size_t)n * (Cc * LL);

    float vals[16];
    float ctr[4];
    float sumsq = 0.f;
#pragma unroll
    for (int ci = 0; ci < 4; ++ci) {
        const float* p = src + (cg * 4 + ci) * LL;
        float t0 = (y > 0 && x > 0)  ? p[l - 65] : 0.f;
        float t1 = (y > 0)           ? p[l - 64] : 0.f;
        float t2 = (y > 0 && x < 63) ? p[l - 63] : 0.f;
        float t3 = (x > 0)           ? p[l - 1]  : 0.f;
        ctr[ci] = p[l];
        vals[ci * 4 + 0] = t0; vals[ci * 4 + 1] = t1;
        vals[ci * 4 + 2] = t2; vals[ci * 4 + 3] = t3;
        sumsq += t0 * t0 + t1 * t1 + t2 * t2 + t3 * t3;
    }
    sumsq += __shfl_xor(sumsq, 1, 64);
    sumsq += __shfl_xor(sumsq, 2, 64);
    sumsq += __shfl_xor(sumsq, 4, 64);
    sumsq += __shfl_xor(sumsq, 8, 64);
    float inv = 1.f / fmaxf(sqrtf(sumsq), 1e-12f);

    // channel-contiguous transpose for writeout (16 threads x 16B = 256B/row)
    f32x4 cv; cv.x = ctr[0]; cv.y = ctr[1]; cv.z = ctr[2]; cv.w = ctr[3];
    *(f32x4*)(yhatT + ((size_t)n * LL + l) * 64 + cg * 4) = cv;

    // fragment-packed destination: 1KB chunk (rowblk,cg) + row slot
    size_t pk = ((((size_t)n * 128 + (l >> 5)) * 16 + cg) << 9) + (l & 31) * 8;
    unsigned short* dh = VhT + pk;
    unsigned short* dl = VlT + pk;
    ushort8v hA, hB, lA, lB;
#pragma unroll
    for (int kk = 0; kk < 16; ++kk) {           // kk = ci*4 + tp = k within chunk
        float v = vals[kk] * inv;
        _Float16 h = (fabsf(v) < 6.1035e-5f) ? (_Float16)0 : (_Float16)v;
        _Float16 lo = (_Float16)((v - (float)h) * 2048.0f);
        unsigned short hu = h2u(h * (_Float16)2048.0f);   // exact pow2 scale
        unsigned short lu = h2u(lo);
        if (kk < 8) { hA[kk] = hu; lA[kk] = lu; }
        else        { hB[kk - 8] = hu; lB[kk - 8] = lu; }
    }
    *(ushort8v*)(dh)       = hA;   // k8-half 0
    *(ushort8v*)(dh + 256) = hB;   // k8-half 1 (+256 halves = +512B)
    *(ushort8v*)(dl)       = lA;
    *(ushort8v*)(dl + 256) = lB;
}

// Kernel 2: triangular 128x128-tiled similarity-max via split-fp16 32x32x16 MFMA.
// acc = Al'Bh' + Ah'Bl + Ah'Bh' = 2^22 * v1.v2 ; val = acc * 2^-22.
// k16-granular staging into a RING of 3 x 16KB LDS buffers (48KB -> 3 blocks/CU)
// via global_load_lds; 16 phases, each:
//   pipe_barrier(vmcnt(4))  -- counted: newest glds batch stays in flight
//   issue next k16's 4 glds (into the buffer this barrier just freed)
//   8 ds_read_b128 fragment loads; MFMA sub-cluster
// Phase A carries pass1-kc0 (4 MFMA), phase B the remaining 20 -- per-acc-element
// accumulation order (p1kc0,p1kc1,p2kc0,p2kc1,p3kc0,p3kc1) is IDENTICAL to all
// prior versions -> bit-exact.
// Ring math: k16 kq lives in buf kq%3. Chunk idx in buffer: side*8+rb*2+lo.
__global__ __launch_bounds__(256) void simmax(const unsigned short* __restrict__ Vh,
                                              const unsigned short* __restrict__ Vl,
                                              unsigned long long* __restrict__ best) {
    __shared__ __align__(16) unsigned short S[24576];   // 3 bufs x 16 chunks x 1KB = 48KB

    int bx = blockIdx.x;              // 0..2111
    int xcd = bx & 7, idx = bx >> 3;  // XCD-pin: each XCD owns half of one batch
    int n = xcd >> 1;
    int t = (xcd & 1) * 264 + idx;    // 0..527
    int j = (int)((sqrtf(8.f * (float)t + 1.f) - 1.f) * 0.5f);
    while ((j + 1) * (j + 2) / 2 <= t) ++j;
    while (j * (j + 1) / 2 > t) --j;
    int i = t - j * (j + 1) / 2;
    int l0 = i * 128, m0 = j * 128;

    int tid = threadIdx.x;
    int w = tid >> 6, lane = tid & 63;
    int r5 = lane & 31, h5 = lane >> 5;
    int rw = (w & 1) * 64;    // wave rows (l)
    int cw = (w >> 1) * 64;   // wave cols (m)
    bool skip = (i == j) && (rw == 64) && (cw == 0);  // fully l>m: no compute

    const unsigned short* VhB = Vh + (size_t)n * (LL * KK);
    const unsigned short* VlB = Vl + (size_t)n * (LL * KK);

    int aRow0 = l0 >> 5;              // block's first A rowblock (of 4)
    int bRow0 = m0 >> 5;              // block's first B rowblock (of 4)

    // staging: per k16 phase, wave w stages chunk idx = w*4+q (q=0..3)
    const unsigned short* gsrc[4];
    int lslot[4];
#pragma unroll
    for (int q = 0; q < 4; ++q) {
        int cidx = w * 4 + q;
        int side = cidx >> 3, rb = (cidx >> 1) & 3, lo = cidx & 1;
        int rowblk = (side ? bRow0 : aRow0) + rb;
        gsrc[q] = (lo ? VlB : VhB) + ((size_t)(rowblk * 16) << 9) + lane * 8;
        lslot[q] = cidx * 512;
    }

    int arb = (w & 1) * 2;            // wave A rowblock base (0 or 2)
    int brb = (w >> 1) * 2;           // wave B rowblock base

    f32x16 acc[2][2];
#pragma unroll
    for (int r = 0; r < 2; ++r)
#pragma unroll
        for (int c = 0; c < 2; ++c) acc[r][c] = (f32x16)0.f;

#define GLDS(KQ, BN)                                                              \
    do {                                                                          \
        _Pragma("unroll")                                                         \
        for (int q = 0; q < 4; ++q)                                               \
            __builtin_amdgcn_global_load_lds(                                     \
                (const __attribute__((address_space(1))) void*)(gsrc[q] + (size_t)(KQ) * 512), \
                (__attribute__((address_space(3))) void*)(S + (BN) * 8192 + lslot[q]), 16, 0, 0); \
    } while (0)

    // prologue: stage k16=0 -> buf0, k16=1 -> buf1 (8 glds in flight)
    GLDS(0, 0);
    GLDS(1, 1);

#pragma unroll
    for (int kt = 0; kt < 8; ++kt) {
        const int b0 = (2 * kt) % 3;       // buffer holding kc0 (k16 = 2kt)
        const int b1 = (2 * kt + 1) % 3;   // buffer holding kc1

        half8 al[2][2], ah[2][2], bl[2][2], bh[2][2];

        // ---- phase A: barrier (k16=2kt landed; frees buf (2kt+2)%3),
        //      stage k16=2kt+2, read kc0 frags, pass1-kc0 MFMAs
        pipe_barrier_vm4();
        if (kt < 7) GLDS(2 * kt + 2, (2 * kt + 2) % 3);
        if (!skip) {
#pragma unroll
            for (int r = 0; r < 2; ++r) {
                al[r][0] = *(const half8*)(S + b0 * 8192 + ((arb + r) * 2 + 1) * 512 + lane * 8);
                bh[r][0] = *(const half8*)(S + b0 * 8192 + (8 + (brb + r) * 2) * 512 + lane * 8);
            }
#pragma unroll
            for (int r = 0; r < 2; ++r) {
                ah[r][0] = *(const half8*)(S + b0 * 8192 + ((arb + r) * 2) * 512 + lane * 8);
                bl[r][0] = *(const half8*)(S + b0 * 8192 + (9 + (brb + r) * 2) * 512 + lane * 8);
            }
            __builtin_amdgcn_s_setprio(1);
#pragma unroll
            for (int r = 0; r < 2; ++r)
#pragma unroll
                for (int c = 0; c < 2; ++c)
                    acc[r][c] = __builtin_amdgcn_mfma_f32_32x32x16_f16(al[r][0], bh[c][0], acc[r][c], 0, 0, 0);
            __builtin_amdgcn_s_setprio(0);
        }

        // ---- phase B: barrier (k16=2kt+1 landed; frees buf b0 for k16=2kt+3),
        //      stage k16=2kt+3, read kc1 frags, remaining 20 MFMAs
        if (kt < 7) pipe_barrier_vm4();
        else        pipe_barrier_vm0();     // tail: nothing newer in flight
        if (kt < 7) GLDS(2 * kt + 3, (2 * kt + 3) % 3);

        if (!skip) {
#pragma unroll
            for (int r = 0; r < 2; ++r) {
                al[r][1] = *(const half8*)(S + b1 * 8192 + ((arb + r) * 2 + 1) * 512 + lane * 8);
                bh[r][1] = *(const half8*)(S + b1 * 8192 + (8 + (brb + r) * 2) * 512 + lane * 8);
            }
#pragma unroll
            for (int r = 0; r < 2; ++r) {
                ah[r][1] = *(const half8*)(S + b1 * 8192 + ((arb + r) * 2) * 512 + lane * 8);
                bl[r][1] = *(const half8*)(S + b1 * 8192 + (9 + (brb + r) * 2) * 512 + lane * 8);
            }
            __builtin_amdgcn_s_setprio(1);
            // p1kc1, then p2kc0,p2kc1, p3kc0,p3kc1 -- order per acc element preserved
#pragma unroll
            for (int r = 0; r < 2; ++r)
#pragma unroll
                for (int c = 0; c < 2; ++c)
                    acc[r][c] = __builtin_amdgcn_mfma_f32_32x32x16_f16(al[r][1], bh[c][1], acc[r][c], 0, 0, 0);
#pragma unroll
            for (int kc = 0; kc < 2; ++kc)
#pragma unroll
                for (int r = 0; r < 2; ++r)
#pragma unroll
                    for (int c = 0; c < 2; ++c)
                        acc[r][c] = __builtin_amdgcn_mfma_f32_32x32x16_f16(ah[r][kc], bl[c][kc], acc[r][c], 0, 0, 0);
#pragma unroll
            for (int kc = 0; kc < 2; ++kc)
#pragma unroll
                for (int r = 0; r < 2; ++r)
#pragma unroll
                    for (int c = 0; c < 2; ++c)
                        acc[r][c] = __builtin_amdgcn_mfma_f32_32x32x16_f16(ah[r][kc], bh[c][kc], acc[r][c], 0, 0, 0);
            __builtin_amdgcn_s_setprio(0);
        }
    }
#undef GLDS

    if (skip) return;
    unsigned long long* bb = best + (size_t)n * LL;
    const float s = 1.f / 4194304.f;   // 2^-22
#pragma unroll
    for (int c = 0; c < 2; ++c) {
        int m = m0 + cw + c * 32 + r5;
        unsigned long long key = 0ull;
#pragma unroll
        for (int r = 0; r < 2; ++r)
#pragma unroll
            for (int g = 0; g < 16; ++g) {
                int l = l0 + rw + r * 32 + (g & 3) + 8 * (g >> 2) + 4 * h5;
                if (l < m) {
                    float v = acc[r][c][g] * s;
                    unsigned long long k2 =
                        ((unsigned long long)f2ord(v) << 32) |
                        (unsigned long long)(0xFFFFFFFFu - (unsigned)l);
                    key = (k2 > key) ? k2 : key;
                }
            }
        unsigned long long o = __shfl_xor(key, 32, 64);
        key = (o > key) ? o : key;
        if (h5 == 0 && key != 0ull) atomicMax(bb + m, key);
    }
}

// Kernel 3: unpack best, write S, U, ref_unfold, arg. Gather reads the
// channel-contiguous yhatT with lanes spanning c (coalesced 256B runs per m),
// transposes [patch][c] -> [f][m] through padded LDS, stores Rout coalesced.
// Block = (n, 16 m's). 1024 blocks, XCD-pinned.
__global__ __launch_bounds__(256) void writeout(const float* __restrict__ yhatT,
                                                const float* __restrict__ yprob,
                                                const unsigned long long* __restrict__ best,
                                                float* __restrict__ out) {
    __shared__ float P[576 * 17];             // [f][m] stride 17 (bank-spread), 39168B

    int blk = blockIdx.x;                     // 0..1023
    int xcd = blk & 7;
    int n = xcd >> 1;
    int mb = (blk >> 3) + (xcd & 1) * 128;    // 0..255
    int m0 = mb * 16;
    int tid = threadIdx.x;
    int ml = tid >> 4;                        // m_local 0..15
    int cs = (tid & 15) * 4;                  // channel start 0,4,..,60
    int m = m0 + ml;

    unsigned long long key = best[(size_t)n * LL + m];
    unsigned l = 0xFFFFFFFFu - (unsigned)(key & 0xFFFFFFFFull);
    float val = ord2f((unsigned)(key >> 32));
    bool zero = (m == 0);
    if (zero) l = 0;
    int ly = (int)(l >> 6), lx = (int)(l & 63);

    float* Sout = out;                       // [4,1,64,64]
    float* Uout = out + 16384;               // [4,1,64,64]
    float* Rout = out + 32768;               // [4,576,4096]
    float* Aout = out + 9469952;             // [4,4096] as float values

    if (cs == 0) {                            // one thread per m
        float S = zero ? 1e-8f : fminf(fmaxf(val, 1e-8f), 1.0f);
        float U = zero ? 1e-8f : fminf(fmaxf(yprob[(size_t)n * LL + l], 1e-8f), 1.0f);
        Sout[(size_t)n * LL + m] = S;
        Uout[(size_t)n * LL + m] = U;
        Aout[(size_t)n * LL + m] = zero ? -1.0f : (float)l;
    }

    // phase 1: gather 3x3 patch rows channel-contiguous, scatter into LDS [f][m]
    const float* T = yhatT + ((size_t)n * LL) * 64;
#pragma unroll
    for (int i = 0; i < 3; ++i) {
        int yy = ly + i - 1;
        bool rok = (!zero) && (yy >= 0) && (yy < 64);
#pragma unroll
        for (int jj = 0; jj < 3; ++jj) {
            int xx = lx + jj - 1;
            f32x4 v; v.x = 0.f; v.y = 0.f; v.z = 0.f; v.w = 0.f;
            if (rok && xx >= 0 && xx < 64)
                v = *(const f32x4*)(T + ((size_t)(yy * 64 + xx)) * 64 + cs);
            int ij = i * 3 + jj;
            P[((cs + 0) * 9 + ij) * 17 + ml] = v.x;
            P[((cs + 1) * 9 + ij) * 17 + ml] = v.y;
            P[((cs + 2) * 9 + ij) * 17 + ml] = v.z;
            P[((cs + 3) * 9 + ij) * 17 + ml] = v.w;
        }
    }
    __syncthreads();

    // phase 2: coalesced Rout stores (wave = 4 f x 16 m -> 4x64B segments)
    float* R = Rout + (size_t)n * (576 * LL) + m0;
    int fl = tid >> 4;                        // f offset within iteration
    int mm2 = tid & 15;
#pragma unroll 1
    for (int it2 = 0; it2 < 36; ++it2) {
        int f = it2 * 16 + fl;
        float v = P[f * 17 + mm2];
        __builtin_nontemporal_store(v, R + (size_t)f * LL + mm2);
    }
}

extern "C" void kernel_launch(void* const* d_in, const int* in_sizes, int n_in,
                              void* d_out, int out_size, void* d_ws, size_t ws_size,
                              hipStream_t stream) {
    const float* yhat  = (const float*)d_in[0];
    const float* yprob = (const float*)d_in[1];
    float* out = (float*)d_out;

    unsigned short* VhT = (unsigned short*)d_ws;                       // 8 MiB (fragment-packed)
    unsigned short* VlT = (unsigned short*)((char*)d_ws + 8388608);    // 8 MiB (fragment-packed)
    unsigned long long* best =
        (unsigned long long*)((char*)d_ws + 16777216);                 // 128 KiB
    float* yhatT = (float*)((char*)d_ws + 16908288);                   // 4 MiB transpose

    build_v<<<1024, 256, 0, stream>>>(yhat, VhT, VlT, yhatT, best);
    simmax<<<Nn * TRI2, 256, 0, stream>>>(VhT, VlT, best);
    writeout<<<1024, 256, 0, stream>>>(yhatT, yprob, best, out);
}

// Round 7
// 151.465 us; speedup vs baseline: 1.0323x; 1.0084x over previous
//
#include <hip/hip_runtime.h>
#include <stdint.h>

#define Nn 4
#define Cc 64
#define LL 4096   // H*W
#define KK 256    // feature dim: 64 channels * 4 causal taps
#define TRI2 528  // 32*33/2 triangular 128x128 tile pairs per batch

typedef _Float16 half8 __attribute__((ext_vector_type(8)));
typedef float f32x16 __attribute__((ext_vector_type(16)));
typedef float f32x4 __attribute__((ext_vector_type(4)));           // 16B aligned
typedef unsigned short ushort8v __attribute__((ext_vector_type(8)));

__device__ __forceinline__ unsigned f2ord(float f) {
    unsigned u = __float_as_uint(f);
    return u ^ ((u & 0x80000000u) ? 0xFFFFFFFFu : 0x80000000u);
}
__device__ __forceinline__ float ord2f(unsigned o) {
    unsigned u = (o & 0x80000000u) ? (o ^ 0x80000000u) : ~o;
    return __uint_as_float(u);
}
__device__ __forceinline__ unsigned short h2u(_Float16 h) {
    union { _Float16 f; unsigned short u; } x; x.f = h; return x.u;
}

// Raw barrier with COUNTED vmcnt (T4, m201-template pattern): the newest
// glds batches stay in flight across the barrier; only older batches are
// guaranteed landed. lgkmcnt(0) before s_barrier closes the LDS
// read-before-overwrite hazard.
__device__ __forceinline__ void pipe_barrier_vm4() {
    asm volatile("s_waitcnt lgkmcnt(0) vmcnt(4)" ::: "memory");
    __builtin_amdgcn_s_barrier();
    __builtin_amdgcn_sched_barrier(0);
}
__device__ __forceinline__ void pipe_barrier_vm0() {
    asm volatile("s_waitcnt lgkmcnt(0) vmcnt(0)" ::: "memory");
    __builtin_amdgcn_s_barrier();
    __builtin_amdgcn_sched_barrier(0);
}

// Kernel 1: normalized masked context vectors, split fp16 hi/lo, both pre-scaled:
//   Vh' = 2048*fp16(v)  (exact pow2),  Vl = fp16((v - fp16(v)) * 2048)
// Both MFMA-FRAGMENT-PACKED:
//   addr(n,l,k) = (((n*128+(l>>5))*16+(k>>4))<<9) + ((k>>3)&1)*256 + (l&31)*8 + (k&7)
// ALSO emits yhatT[n][l][c] (channel-contiguous transpose) for writeout's gather.
// XCD-pinned and zeroes its slice of `best`.
__global__ __launch_bounds__(256) void build_v(const float* __restrict__ yhat,
                                               unsigned short* __restrict__ VhT,
                                               unsigned short* __restrict__ VlT,
                                               float* __restrict__ yhatT,
                                               unsigned long long* __restrict__ best) {
    int blk = blockIdx.x;                       // 0..1023
    int xcd = blk & 7;
    int n = xcd >> 1;
    int i64 = (blk >> 3) + (xcd & 1) * 128;     // 0..255; block covers l = i64*16 ..+16
    int tid = threadIdx.x;
    if (tid < 16) best[(size_t)n * LL + i64 * 16 + tid] = 0ull;

    int cg = tid & 15;           // channel group 0..15 (4 channels each) == k16 chunk
    int l = i64 * 16 + (tid >> 4);
    int y = l >> 6, x = l & 63;
    const float* src = yhat + (size_t)n * (Cc * LL);

    float vals[16];
    float ctr[4];
    float sumsq = 0.f;
#pragma unroll
    for (int ci = 0; ci < 4; ++ci) {
        const float* p = src + (cg * 4 + ci) * LL;
        float t0 = (y > 0 && x > 0)  ? p[l - 65] : 0.f;
        float t1 = (y > 0)           ? p[l - 64] : 0.f;
        float t2 = (y > 0 && x < 63) ? p[l - 63] : 0.f;
        float t3 = (x > 0)           ? p[l - 1]  : 0.f;
        ctr[ci] = p[l];
        vals[ci * 4 + 0] = t0; vals[ci * 4 + 1] = t1;
        vals[ci * 4 + 2] = t2; vals[ci * 4 + 3] = t3;
        sumsq += t0 * t0 + t1 * t1 + t2 * t2 + t3 * t3;
    }
    sumsq += __shfl_xor(sumsq, 1, 64);
    sumsq += __shfl_xor(sumsq, 2, 64);
    sumsq += __shfl_xor(sumsq, 4, 64);
    sumsq += __shfl_xor(sumsq, 8, 64);
    float inv = 1.f / fmaxf(sqrtf(sumsq), 1e-12f);

    // channel-contiguous transpose for writeout (16 threads x 16B = 256B/row)
    f32x4 cv; cv.x = ctr[0]; cv.y = ctr[1]; cv.z = ctr[2]; cv.w = ctr[3];
    *(f32x4*)(yhatT + ((size_t)n * LL + l) * 64 + cg * 4) = cv;

    // fragment-packed destination: 1KB chunk (rowblk,cg) + row slot
    size_t pk = ((((size_t)n * 128 + (l >> 5)) * 16 + cg) << 9) + (l & 31) * 8;
    unsigned short* dh = VhT + pk;
    unsigned short* dl = VlT + pk;
    ushort8v hA, hB, lA, lB;
#pragma unroll
    for (int kk = 0; kk < 16; ++kk) {           // kk = ci*4 + tp = k within chunk
        float v = vals[kk] * inv;
        _Float16 h = (fabsf(v) < 6.1035e-5f) ? (_Float16)0 : (_Float16)v;
        _Float16 lo = (_Float16)((v - (float)h) * 2048.0f);
        unsigned short hu = h2u(h * (_Float16)2048.0f);   // exact pow2 scale
        unsigned short lu = h2u(lo);
        if (kk < 8) { hA[kk] = hu; lA[kk] = lu; }
        else        { hB[kk - 8] = hu; lB[kk - 8] = lu; }
    }
    *(ushort8v*)(dh)       = hA;   // k8-half 0
    *(ushort8v*)(dh + 256) = hB;   // k8-half 1 (+256 halves = +512B)
    *(ushort8v*)(dl)       = lA;
    *(ushort8v*)(dl + 256) = lB;
}

// Kernel 2: triangular 128x128-tiled similarity-max via split-fp16 32x32x16 MFMA.
// acc = Al'Bh' + Ah'Bl + Ah'Bh' = 2^22 * v1.v2 ; val = acc * 2^-22.
// Pipeline (unchanged from R6): k16-granular staging into a RING of 3 x 16KB LDS
// buffers via global_load_lds; 16 phases with counted-vmcnt raw barriers.
// NEW (R7): SUPERTILE tile->block mapping for L2 locality. The triangle of 528
// tiles per batch is enumerated in 512x512 supertiles (4x4 groups of 128-tiles;
// diagonal STs hold 10 tiles, off-diagonal 16). Working set per supertile is
// ~1MB (512 A-rows + 512 B-rows, hi+lo) -> fits the 4MB per-XCD L2, where the
// old enumeration walked ~32 distinct A-panels concurrently and thrashed L2
// (glds returns at L3/HBM latency -> the measured 3.4Kcy phases).
// Column-major ST enumeration: cumulative C(J) = 8J^2+2J; within column J,
// r<16J -> off-diag (I=r>>4, di=inner&3, dj=inner>>2), else diag triangular-10.
// Fragment bytes and per-acc-element accumulation order bit-identical.
__global__ __launch_bounds__(256) void simmax(const unsigned short* __restrict__ Vh,
                                              const unsigned short* __restrict__ Vl,
                                              unsigned long long* __restrict__ best) {
    __shared__ __align__(16) unsigned short S[24576];   // 3 bufs x 16 chunks x 1KB = 48KB

    int bx = blockIdx.x;              // 0..2111
    int xcd = bx & 7, idx = bx >> 3;  // XCD-pin: each XCD owns half of one batch
    int n = xcd >> 1;
    int t = (xcd & 1) * 264 + idx;    // 0..527

    // supertile decode: column J, then off-diag/diag split
    int J = (int)((sqrtf(32.f * (float)t + 4.f) - 2.f) * 0.0625f);
    while (8 * (J + 1) * (J + 1) + 2 * (J + 1) <= t) ++J;
    while (8 * J * J + 2 * J > t) --J;
    int r = t - (8 * J * J + 2 * J);
    int i, j;
    if (r < 16 * J) {                 // off-diagonal supertile (I,J), I<J: 16 tiles
        int I = r >> 4, inner = r & 15;
        i = 4 * I + (inner & 3);
        j = 4 * J + (inner >> 2);
    } else {                          // diagonal supertile (J,J): 10 tiles, di<=dj
        int rr = r - 16 * J;
        int dj = (rr >= 6) ? 3 : (rr >= 3) ? 2 : (rr >= 1) ? 1 : 0;
        int di = rr - ((dj * (dj + 1)) >> 1);
        i = 4 * J + di;
        j = 4 * J + dj;
    }
    int l0 = i * 128, m0 = j * 128;

    int tid = threadIdx.x;
    int w = tid >> 6, lane = tid & 63;
    int r5 = lane & 31, h5 = lane >> 5;
    int rw = (w & 1) * 64;    // wave rows (l)
    int cw = (w >> 1) * 64;   // wave cols (m)
    bool skip = (i == j) && (rw == 64) && (cw == 0);  // fully l>m: no compute

    const unsigned short* VhB = Vh + (size_t)n * (LL * KK);
    const unsigned short* VlB = Vl + (size_t)n * (LL * KK);

    int aRow0 = l0 >> 5;              // block's first A rowblock (of 4)
    int bRow0 = m0 >> 5;              // block's first B rowblock (of 4)

    // staging: per k16 phase, wave w stages chunk idx = w*4+q (q=0..3)
    const unsigned short* gsrc[4];
    int lslot[4];
#pragma unroll
    for (int q = 0; q < 4; ++q) {
        int cidx = w * 4 + q;
        int side = cidx >> 3, rb = (cidx >> 1) & 3, lo = cidx & 1;
        int rowblk = (side ? bRow0 : aRow0) + rb;
        gsrc[q] = (lo ? VlB : VhB) + ((size_t)(rowblk * 16) << 9) + lane * 8;
        lslot[q] = cidx * 512;
    }

    int arb = (w & 1) * 2;            // wave A rowblock base (0 or 2)
    int brb = (w >> 1) * 2;           // wave B rowblock base

    f32x16 acc[2][2];
#pragma unroll
    for (int r2 = 0; r2 < 2; ++r2)
#pragma unroll
        for (int c = 0; c < 2; ++c) acc[r2][c] = (f32x16)0.f;

#define GLDS(KQ, BN)                                                              \
    do {                                                                          \
        _Pragma("unroll")                                                         \
        for (int q = 0; q < 4; ++q)                                               \
            __builtin_amdgcn_global_load_lds(                                     \
                (const __attribute__((address_space(1))) void*)(gsrc[q] + (size_t)(KQ) * 512), \
                (__attribute__((address_space(3))) void*)(S + (BN) * 8192 + lslot[q]), 16, 0, 0); \
    } while (0)

    // prologue: stage k16=0 -> buf0, k16=1 -> buf1 (8 glds in flight)
    GLDS(0, 0);
    GLDS(1, 1);

#pragma unroll
    for (int kt = 0; kt < 8; ++kt) {
        const int b0 = (2 * kt) % 3;       // buffer holding kc0 (k16 = 2kt)
        const int b1 = (2 * kt + 1) % 3;   // buffer holding kc1

        half8 al[2][2], ah[2][2], bl[2][2], bh[2][2];

        // ---- phase A: barrier (k16=2kt landed; frees buf (2kt+2)%3),
        //      stage k16=2kt+2, read kc0 frags, pass1-kc0 MFMAs
        pipe_barrier_vm4();
        if (kt < 7) GLDS(2 * kt + 2, (2 * kt + 2) % 3);
        if (!skip) {
#pragma unroll
            for (int r2 = 0; r2 < 2; ++r2) {
                al[r2][0] = *(const half8*)(S + b0 * 8192 + ((arb + r2) * 2 + 1) * 512 + lane * 8);
                bh[r2][0] = *(const half8*)(S + b0 * 8192 + (8 + (brb + r2) * 2) * 512 + lane * 8);
            }
#pragma unroll
            for (int r2 = 0; r2 < 2; ++r2) {
                ah[r2][0] = *(const half8*)(S + b0 * 8192 + ((arb + r2) * 2) * 512 + lane * 8);
                bl[r2][0] = *(const half8*)(S + b0 * 8192 + (9 + (brb + r2) * 2) * 512 + lane * 8);
            }
            __builtin_amdgcn_s_setprio(1);
#pragma unroll
            for (int r2 = 0; r2 < 2; ++r2)
#pragma unroll
                for (int c = 0; c < 2; ++c)
                    acc[r2][c] = __builtin_amdgcn_mfma_f32_32x32x16_f16(al[r2][0], bh[c][0], acc[r2][c], 0, 0, 0);
            __builtin_amdgcn_s_setprio(0);
        }

        // ---- phase B: barrier (k16=2kt+1 landed; frees buf b0 for k16=2kt+3),
        //      stage k16=2kt+3, read kc1 frags, remaining 20 MFMAs
        if (kt < 7) pipe_barrier_vm4();
        else        pipe_barrier_vm0();     // tail: nothing newer in flight
        if (kt < 7) GLDS(2 * kt + 3, (2 * kt + 3) % 3);

        if (!skip) {
#pragma unroll
            for (int r2 = 0; r2 < 2; ++r2) {
                al[r2][1] = *(const half8*)(S + b1 * 8192 + ((arb + r2) * 2 + 1) * 512 + lane * 8);
                bh[r2][1] = *(const half8*)(S + b1 * 8192 + (8 + (brb + r2) * 2) * 512 + lane * 8);
            }
#pragma unroll
            for (int r2 = 0; r2 < 2; ++r2) {
                ah[r2][1] = *(const half8*)(S + b1 * 8192 + ((arb + r2) * 2) * 512 + lane * 8);
                bl[r2][1] = *(const half8*)(S + b1 * 8192 + (9 + (brb + r2) * 2) * 512 + lane * 8);
            }
            __builtin_amdgcn_s_setprio(1);
            // p1kc1, then p2kc0,p2kc1, p3kc0,p3kc1 -- order per acc element preserved
#pragma unroll
            for (int r2 = 0; r2 < 2; ++r2)
#pragma unroll
                for (int c = 0; c < 2; ++c)
                    acc[r2][c] = __builtin_amdgcn_mfma_f32_32x32x16_f16(al[r2][1], bh[c][1], acc[r2][c], 0, 0, 0);
#pragma unroll
            for (int kc = 0; kc < 2; ++kc)
#pragma unroll
                for (int r2 = 0; r2 < 2; ++r2)
#pragma unroll
                    for (int c = 0; c < 2; ++c)
                        acc[r2][c] = __builtin_amdgcn_mfma_f32_32x32x16_f16(ah[r2][kc], bl[c][kc], acc[r2][c], 0, 0, 0);
#pragma unroll
            for (int kc = 0; kc < 2; ++kc)
#pragma unroll
                for (int r2 = 0; r2 < 2; ++r2)
#pragma unroll
                    for (int c = 0; c < 2; ++c)
                        acc[r2][c] = __builtin_amdgcn_mfma_f32_32x32x16_f16(ah[r2][kc], bh[c][kc], acc[r2][c], 0, 0, 0);
            __builtin_amdgcn_s_setprio(0);
        }
    }
#undef GLDS

    if (skip) return;
    unsigned long long* bb = best + (size_t)n * LL;
    const float s = 1.f / 4194304.f;   // 2^-22
#pragma unroll
    for (int c = 0; c < 2; ++c) {
        int m = m0 + cw + c * 32 + r5;
        unsigned long long key = 0ull;
#pragma unroll
        for (int r2 = 0; r2 < 2; ++r2)
#pragma unroll
            for (int g = 0; g < 16; ++g) {
                int l = l0 + rw + r2 * 32 + (g & 3) + 8 * (g >> 2) + 4 * h5;
                if (l < m) {
                    float v = acc[r2][c][g] * s;
                    unsigned long long k2 =
                        ((unsigned long long)f2ord(v) << 32) |
                        (unsigned long long)(0xFFFFFFFFu - (unsigned)l);
                    key = (k2 > key) ? k2 : key;
                }
            }
        unsigned long long o = __shfl_xor(key, 32, 64);
        key = (o > key) ? o : key;
        if (h5 == 0 && key != 0ull) atomicMax(bb + m, key);
    }
}

// Kernel 3: unpack best, write S, U, ref_unfold, arg. Gather reads the
// channel-contiguous yhatT with lanes spanning c (coalesced 256B runs per m),
// transposes [patch][c] -> [f][m] through padded LDS, stores Rout coalesced.
// Block = (n, 16 m's). 1024 blocks, XCD-pinned.
__global__ __launch_bounds__(256) void writeout(const float* __restrict__ yhatT,
                                                const float* __restrict__ yprob,
                                                const unsigned long long* __restrict__ best,
                                                float* __restrict__ out) {
    __shared__ float P[576 * 17];             // [f][m] stride 17 (bank-spread), 39168B

    int blk = blockIdx.x;                     // 0..1023
    int xcd = blk & 7;
    int n = xcd >> 1;
    int mb = (blk >> 3) + (xcd & 1) * 128;    // 0..255
    int m0 = mb * 16;
    int tid = threadIdx.x;
    int ml = tid >> 4;                        // m_local 0..15
    int cs = (tid & 15) * 4;                  // channel start 0,4,..,60
    int m = m0 + ml;

    unsigned long long key = best[(size_t)n * LL + m];
    unsigned l = 0xFFFFFFFFu - (unsigned)(key & 0xFFFFFFFFull);
    float val = ord2f((unsigned)(key >> 32));
    bool zero = (m == 0);
    if (zero) l = 0;
    int ly = (int)(l >> 6), lx = (int)(l & 63);

    float* Sout = out;                       // [4,1,64,64]
    float* Uout = out + 16384;               // [4,1,64,64]
    float* Rout = out + 32768;               // [4,576,4096]
    float* Aout = out + 9469952;             // [4,4096] as float values

    if (cs == 0) {                            // one thread per m
        float S = zero ? 1e-8f : fminf(fmaxf(val, 1e-8f), 1.0f);
        float U = zero ? 1e-8f : fminf(fmaxf(yprob[(size_t)n * LL + l], 1e-8f), 1.0f);
        Sout[(size_t)n * LL + m] = S;
        Uout[(size_t)n * LL + m] = U;
        Aout[(size_t)n * LL + m] = zero ? -1.0f : (float)l;
    }

    // phase 1: gather 3x3 patch rows channel-contiguous, scatter into LDS [f][m]
    const float* T = yhatT + ((size_t)n * LL) * 64;
#pragma unroll
    for (int i = 0; i < 3; ++i) {
        int yy = ly + i - 1;
        bool rok = (!zero) && (yy >= 0) && (yy < 64);
#pragma unroll
        for (int jj = 0; jj < 3; ++jj) {
            int xx = lx + jj - 1;
            f32x4 v; v.x = 0.f; v.y = 0.f; v.z = 0.f; v.w = 0.f;
            if (rok && xx >= 0 && xx < 64)
                v = *(const f32x4*)(T + ((size_t)(yy * 64 + xx)) * 64 + cs);
            int ij = i * 3 + jj;
            P[((cs + 0) * 9 + ij) * 17 + ml] = v.x;
            P[((cs + 1) * 9 + ij) * 17 + ml] = v.y;
            P[((cs + 2) * 9 + ij) * 17 + ml] = v.z;
            P[((cs + 3) * 9 + ij) * 17 + ml] = v.w;
        }
    }
    __syncthreads();

    // phase 2: coalesced Rout stores (wave = 4 f x 16 m -> 4x64B segments)
    float* R = Rout + (size_t)n * (576 * LL) + m0;
    int fl = tid >> 4;                        // f offset within iteration
    int mm2 = tid & 15;
#pragma unroll 1
    for (int it2 = 0; it2 < 36; ++it2) {
        int f = it2 * 16 + fl;
        float v = P[f * 17 + mm2];
        __builtin_nontemporal_store(v, R + (size_t)f * LL + mm2);
    }
}

extern "C" void kernel_launch(void* const* d_in, const int* in_sizes, int n_in,
                              void* d_out, int out_size, void* d_ws, size_t ws_size,
                              hipStream_t stream) {
    const float* yhat  = (const float*)d_in[0];
    const float* yprob = (const float*)d_in[1];
    float* out = (float*)d_out;

    unsigned short* VhT = (unsigned short*)d_ws;                       // 8 MiB (fragment-packed)
    unsigned short* VlT = (unsigned short*)((char*)d_ws + 8388608);    // 8 MiB (fragment-packed)
    unsigned long long* best =
        (unsigned long long*)((char*)d_ws + 16777216);                 // 128 KiB
    float* yhatT = (float*)((char*)d_ws + 16908288);                   // 4 MiB transpose

    build_v<<<1024, 256, 0, stream>>>(yhat, VhT, VlT, yhatT, best);
    simmax<<<Nn * TRI2, 256, 0, stream>>>(VhT, VlT, best);
    writeout<<<1024, 256, 0, stream>>>(yhatT, yprob, best, out);
}